// Round 14
// baseline (3131.785 us; speedup 1.0000x reference)
//
#include <hip/hip_runtime.h>
#include <math.h>

#define EPSF 1e-5f

typedef __attribute__((ext_vector_type(2))) float f2;
typedef __attribute__((ext_vector_type(4))) float f4;
typedef __attribute__((ext_vector_type(8))) _Float16 f16x8;

// DPP helper: v += value from lane (i - N) within the 16-lane DPP row (0 if OOB)
template<int CTRL>
__device__ __forceinline__ float dpp_add(float v) {
    int s = __builtin_amdgcn_update_dpp(0, __float_as_int(v), CTRL, 0xf, 0xf, true);
    return v + __int_as_float(s);
}

// raw barrier: order LDS (lgkmcnt) but leave global loads (vmcnt) in flight.
// All cross-wave deps in k_gru2 are LDS (hq/gsum/tfl/hqh); globals are
// read-only streams or per-thread-exclusive out writes. Precedent: R0's
// DMA-ring kernel used the same pattern in this harness.
#define RAW_BAR() asm volatile("s_waitcnt lgkmcnt(0)\n\ts_barrier" ::: "memory")

// hq swizzle: +4 floats of pad per 16 (stride 20)
#define HQ(d) ((d) + (((d) >> 4) << 2))

// ---------------- prep: weight transposes + bool-dtype detect ----------------
// WhhP: MFMA A-fragment layout (tile-major). W2F/W3Fh/W3Fl: MFMA B-fragment
// layout [tap(25)][cc(4)][cot(8)][lane(64)][e(8)] fp16 (W3 split hi/lo exactly).
__global__ __launch_bounds__(256) void k_prep(
    const float* __restrict__ Wih, const float* __restrict__ Whh,
    const float* __restrict__ W2, const float* __restrict__ W3,
    const unsigned char* __restrict__ fmask,
    unsigned int* __restrict__ WhhP, float* __restrict__ WxT,
    _Float16* __restrict__ W2F, _Float16* __restrict__ W3Fh,
    _Float16* __restrict__ W3Fl, int* __restrict__ flag)
{
    int idx = blockIdx.x * 256 + threadIdx.x;
    if (idx < 98304) {                  // Whh -> MFMA A-frag layout
        int T = idx >> 8;
        int lane = (idx >> 2) & 63;
        int j = idx & 3;
        int RT = T >> 3, kt = T & 7;
        int row = RT * 16 + (lane & 15);
        int col = kt * 32 + (lane >> 4) * 8 + j * 2;
        union { _Float16 h[2]; unsigned int u; } pk;
        pk.h[0] = (_Float16)Whh[row * 256 + col];
        pk.h[1] = (_Float16)Whh[row * 256 + col + 1];
        WhhP[idx] = pk.u;
    }
    if (idx < 105984) {                 // Wih[768][138] x-part -> WxT[128][768]
        int j = idx / 138, k = idx % 138;
        if (k < 128) WxT[k * 768 + j] = Wih[idx];
    }
    if (idx < 409600) {                 // W2/W3 -> B-fragments
        int f = idx & 7, lane = (idx >> 3) & 63, cot = (idx >> 9) & 7;
        int cc = (idx >> 12) & 3, T = idx >> 14;     // T 0..24
        int k = cc * 32 + (lane >> 4) * 8 + f;
        int co = cot * 16 + (lane & 15);
        int dt = T / 5, dm = T % 5;
        W2F[idx] = (_Float16)W2[co * 3200 + k * 25 + dt * 5 + dm];
        float w3v = W3[co * 3200 + k * 25 + dt * 5 + dm];
        _Float16 h3 = (_Float16)w3v;
        W3Fh[idx] = h3;
        W3Fl[idx] = (_Float16)(w3v - (float)h3);
    }
    if (idx == 0) {                     // bool stored as int32?
        int nz = 0;
        for (int i = 0; i < 4096; i++) if ((i & 3) != 0) nz |= fmask[i];
        *flag = nz ? 0 : 1;
    }
}

// ------- conv1: [32,1,1024,40] -> X1h (fp16 hi) + X1l (fp16 residual) -------
__global__ __launch_bounds__(256) void k_conv1(
    const float* __restrict__ X, const float* __restrict__ W1,
    const float* __restrict__ bb, const float* __restrict__ gg,
    const float* __restrict__ be, const float* __restrict__ mm_,
    const float* __restrict__ vv, _Float16* __restrict__ X1h,
    _Float16* __restrict__ X1l)
{
    __shared__ __align__(16) float xs[8][44];
    __shared__ __align__(16) float ws[25][128];
    __shared__ float sc[128], sh[128];
    int bid = blockIdx.x;
    int b = bid >> 8, t0 = (bid & 255) << 2;
    int tid = threadIdx.x;
    for (int e = tid; e < 8 * 44; e += 256) {
        int tt = e / 44, mm = e % 44;
        int gt = t0 + tt - 2, gm = mm - 2;
        float val = 0.f;
        if (gt >= 0 && gt < 1024 && gm >= 0 && gm < 40)
            val = X[(b * 1024 + gt) * 40 + gm];
        xs[tt][mm] = val;
    }
    for (int e = tid; e < 3200; e += 256) {
        int tap = e >> 7, co = e & 127;
        ws[tap][co] = W1[co * 25 + tap];
    }
    if (tid < 128) {
        float s = gg[tid] / sqrtf(vv[tid] + EPSF);
        sc[tid] = s;
        sh[tid] = (bb[tid] - mm_[tid]) * s + be[tid];
    }
    __syncthreads();
    int cog = tid >> 5;          // 8 groups x 16 co
    int m1i = (tid >> 2) & 7;    // pooled mel
    int tp  = tid & 3;           // t'
    int co0 = cog * 16;
    float val[5][16];
#pragma unroll
    for (int p = 0; p < 5; p++)
#pragma unroll
        for (int i = 0; i < 16; i++) val[p][i] = 0.f;
#pragma unroll
    for (int dt = 0; dt < 5; dt++) {
#pragma unroll
        for (int dm = 0; dm < 5; dm++) {
            float w[16];
#pragma unroll
            for (int i = 0; i < 16; i += 4)
                *(float4*)&w[i] = *(const float4*)&ws[dt * 5 + dm][co0 + i];
#pragma unroll
            for (int p = 0; p < 5; p++) {
                float x = xs[tp + dt][m1i * 5 + p + dm];
#pragma unroll
                for (int i = 0; i < 16; i++) val[p][i] = fmaf(x, w[i], val[p][i]);
            }
        }
    }
    f16x8 h0, h1, l0, l1;
#pragma unroll
    for (int i = 0; i < 16; i++) {
        float s = sc[co0 + i], h = sh[co0 + i];
        float mx = 0.f;
#pragma unroll
        for (int p = 0; p < 5; p++) {
            float y = fmaf(val[p][i], s, h);
            y = fmaxf(y, 0.f);
            mx = fmaxf(mx, y);
        }
        _Float16 hh = (_Float16)mx;
        _Float16 ll = (_Float16)(mx - (float)hh);
        if (i < 8) { h0[i] = hh; l0[i] = ll; }
        else       { h1[i - 8] = hh; l1[i - 8] = ll; }
    }
    long off = (((long)(b * 1024 + t0 + tp)) * 8 + m1i) * 128 + co0;
    *(f16x8*)&X1h[off] = h0;
    *(f16x8*)&X1h[off + 8] = h1;
    *(f16x8*)&X1l[off] = l0;
    *(f16x8*)&X1l[off + 8] = l1;
}

// ====== conv2 v7b: MFMA implicit GEMM; outputs exact fp16 hi/lo X2 ======
__global__ __launch_bounds__(256) void k_conv2(
    const _Float16* __restrict__ X1h, const _Float16* __restrict__ X1l,
    const _Float16* __restrict__ W2F,
    const float* __restrict__ bb, const float* __restrict__ gg,
    const float* __restrict__ be, const float* __restrict__ mm_,
    const float* __restrict__ vv, _Float16* __restrict__ X2h,
    _Float16* __restrict__ X2l)
{
    __shared__ __align__(16) _Float16 xsh[144 * 40]; // hi tile
    __shared__ __align__(16) _Float16 xsl[144 * 40]; // lo tile
    __shared__ float sc[128], sh[128];
    int bid = blockIdx.x;
    int b = bid >> 7, t0 = (bid & 127) << 3;
    int tid = threadIdx.x;
    int wv = tid >> 6, l = tid & 63;
    int rowc = l & 15, ks = (l >> 4) << 3;
    int tloc = rowc >> 3, mloc = rowc & 7;
    if (tid < 128) {
        float s = gg[tid] / sqrtf(vv[tid] + EPSF);
        sc[tid] = s;
        sh[tid] = (bb[tid] - mm_[tid]) * s + be[tid];
    }
    f4 acc[4][2];
#pragma unroll
    for (int Mt = 0; Mt < 4; Mt++) {
        acc[Mt][0] = (f4){0.f, 0.f, 0.f, 0.f};
        acc[Mt][1] = (f4){0.f, 0.f, 0.f, 0.f};
    }

    for (int cc = 0; cc < 4; cc++) {
        __syncthreads();
        for (int e = tid; e < 1152; e += 256) {
            int w2 = (e >= 576) ? 1 : 0;
            int ee = e - 576 * w2;
            int r = ee >> 2, q = ee & 3;
            int tt = r / 12, mm2 = r % 12;
            int gt = t0 + tt - 2, gm = mm2 - 2;
            f16x8 v;
#pragma unroll
            for (int z = 0; z < 8; z++) v[z] = (_Float16)0.f;
            if (gt >= 0 && gt < 1024 && gm >= 0 && gm < 8) {
                const _Float16* src = w2 ? X1l : X1h;
                v = *(const f16x8*)&src[(((long)(b * 1024 + gt)) * 8 + gm) * 128 + cc * 32 + q * 8];
            }
            _Float16* dst = w2 ? xsl : xsh;
            *(f16x8*)&dst[r * 40 + q * 8] = v;
        }
        __syncthreads();
        for (int dt = 0; dt < 5; dt++) {
#pragma unroll
            for (int dm = 0; dm < 5; dm++) {
                const _Float16* wb = &W2F[(((long)((dt * 5 + dm) * 4 + cc) * 8) * 64) * 8];
                f16x8 b0 = *(const f16x8*)&wb[((wv * 2 + 0) * 64 + l) * 8];
                f16x8 b1 = *(const f16x8*)&wb[((wv * 2 + 1) * 64 + l) * 8];
#pragma unroll
                for (int Mt = 0; Mt < 4; Mt++) {
                    int ai = ((Mt * 2 + tloc + dt) * 12 + (mloc + dm)) * 40 + ks;
                    f16x8 ah = *(const f16x8*)&xsh[ai];
                    f16x8 al = *(const f16x8*)&xsl[ai];
                    acc[Mt][0] = __builtin_amdgcn_mfma_f32_16x16x32_f16(ah, b0, acc[Mt][0], 0, 0, 0);
                    acc[Mt][0] = __builtin_amdgcn_mfma_f32_16x16x32_f16(al, b0, acc[Mt][0], 0, 0, 0);
                    acc[Mt][1] = __builtin_amdgcn_mfma_f32_16x16x32_f16(ah, b1, acc[Mt][1], 0, 0, 0);
                    acc[Mt][1] = __builtin_amdgcn_mfma_f32_16x16x32_f16(al, b1, acc[Mt][1], 0, 0, 0);
                }
            }
        }
    }
    int g = l >> 4;
    int tof = g >> 1, m2 = g & 1;
#pragma unroll
    for (int Mt = 0; Mt < 4; Mt++) {
        int t = t0 + Mt * 2 + tof;
#pragma unroll
        for (int c2 = 0; c2 < 2; c2++) {
            int co = (wv * 2 + c2) * 16 + rowc;
            float s = sc[co], h = sh[co];
            f4 av = acc[Mt][c2];
            float mx = 0.f;
#pragma unroll
            for (int j = 0; j < 4; j++) {
                float y = fmaf(av[j], s, h);
                y = fmaxf(y, 0.f);
                mx = fmaxf(mx, y);
            }
            long oi = (((long)(b * 1024 + t)) * 2 + m2) * 128 + co;
            _Float16 hh = (_Float16)mx;
            X2h[oi] = hh;
            X2l[oi] = (_Float16)(mx - (float)hh);
        }
    }
}

// ====== conv3 v3: MFMA implicit GEMM, 3-pass exact hi/lo both operands ======
__global__ __launch_bounds__(256) void k_conv3(
    const _Float16* __restrict__ X2h, const _Float16* __restrict__ X2l,
    const _Float16* __restrict__ W3Fh, const _Float16* __restrict__ W3Fl,
    const float* __restrict__ bb, const float* __restrict__ gg,
    const float* __restrict__ be, const float* __restrict__ mm_,
    const float* __restrict__ vv, float* __restrict__ F)
{
    __shared__ __align__(16) _Float16 xsh[24 * 40];
    __shared__ __align__(16) _Float16 xsl[24 * 40];
    __shared__ float sc[128], sh[128];
    int bid = blockIdx.x;
    int b = bid >> 7, t0 = (bid & 127) << 3;
    int tid = threadIdx.x;
    int wv = tid >> 6, l = tid & 63;
    int rowc = l & 15, ks = (l >> 4) << 3;
    if (tid < 128) {
        float s = gg[tid] / sqrtf(vv[tid] + EPSF);
        sc[tid] = s;
        sh[tid] = (bb[tid] - mm_[tid]) * s + be[tid];
    }
    f4 acc[2];
    acc[0] = (f4){0.f, 0.f, 0.f, 0.f};
    acc[1] = (f4){0.f, 0.f, 0.f, 0.f};

    for (int cc = 0; cc < 4; cc++) {
        __syncthreads();
        for (int e = tid; e < 192; e += 256) {
            int w2 = (e >= 96) ? 1 : 0;
            int r = e - 96 * w2;
            int row = r >> 2, q = r & 3;
            int tt = row >> 1, mm2 = row & 1;
            int gt = t0 + tt - 2;
            f16x8 v;
#pragma unroll
            for (int z = 0; z < 8; z++) v[z] = (_Float16)0.f;
            if (gt >= 0 && gt < 1024) {
                const _Float16* src = w2 ? X2l : X2h;
                v = *(const f16x8*)&src[(((long)(b * 1024 + gt)) * 2 + mm2) * 128 + cc * 32 + q * 8];
            }
            _Float16* dst = w2 ? xsl : xsh;
            *(f16x8*)&dst[row * 40 + q * 8] = v;
        }
        __syncthreads();
        for (int dt = 0; dt < 5; dt++) {
#pragma unroll
            for (int dmi = 0; dmi < 3; dmi++) {
                int dm = dmi + 1;
                const long wb = (((long)((dt * 5 + dm) * 4 + cc) * 8) * 64) * 8;
                f16x8 b0h = *(const f16x8*)&W3Fh[wb + ((wv * 2 + 0) * 64 + l) * 8];
                f16x8 b0l = *(const f16x8*)&W3Fl[wb + ((wv * 2 + 0) * 64 + l) * 8];
                f16x8 b1h = *(const f16x8*)&W3Fh[wb + ((wv * 2 + 1) * 64 + l) * 8];
                f16x8 b1l = *(const f16x8*)&W3Fl[wb + ((wv * 2 + 1) * 64 + l) * 8];
                int mprime = (rowc & 1) + dm - 2;
                bool valid = (mprime >= 0) && (mprime <= 1);
                int row = rowc + dt * 2 + dm - 2;
                int ai = valid ? (row * 40 + ks) : 0;
                f16x8 ah = *(const f16x8*)&xsh[ai];
                f16x8 al = *(const f16x8*)&xsl[ai];
                if (!valid) {
#pragma unroll
                    for (int z = 0; z < 8; z++) { ah[z] = (_Float16)0.f; al[z] = (_Float16)0.f; }
                }
                acc[0] = __builtin_amdgcn_mfma_f32_16x16x32_f16(ah, b0h, acc[0], 0, 0, 0);
                acc[0] = __builtin_amdgcn_mfma_f32_16x16x32_f16(ah, b0l, acc[0], 0, 0, 0);
                acc[0] = __builtin_amdgcn_mfma_f32_16x16x32_f16(al, b0h, acc[0], 0, 0, 0);
                acc[1] = __builtin_amdgcn_mfma_f32_16x16x32_f16(ah, b1h, acc[1], 0, 0, 0);
                acc[1] = __builtin_amdgcn_mfma_f32_16x16x32_f16(ah, b1l, acc[1], 0, 0, 0);
                acc[1] = __builtin_amdgcn_mfma_f32_16x16x32_f16(al, b1h, acc[1], 0, 0, 0);
            }
        }
    }
    int g = l >> 4;
#pragma unroll
    for (int c2 = 0; c2 < 2; c2++) {
        int co = (wv * 2 + c2) * 16 + rowc;
        float s = sc[co], h = sh[co];
#pragma unroll
        for (int j2 = 0; j2 < 2; j2++) {
            float y0 = fmaxf(fmaf(acc[c2][j2 * 2], s, h), 0.f);
            float y1 = fmaxf(fmaf(acc[c2][j2 * 2 + 1], s, h), 0.f);
            F[((long)(t0 + g * 2 + j2) * 32 + b) * 128 + co] = fmaxf(y0, y1);
        }
    }
}

// ------- Gx = F @ Wihx.T + bih (+ bhh for r,z cols) : [32768,128]x[128,768] -------
__global__ __launch_bounds__(256) void k_gemm(
    const float* __restrict__ F, const float* __restrict__ WxT,
    const float* __restrict__ bih, const float* __restrict__ bhh,
    float* __restrict__ Gx)
{
    __shared__ __align__(16) float Fs[64][33];
    __shared__ __align__(16) float Ws[32][256];
    int bid = blockIdx.x;
    int jt = bid % 3, tb0 = (bid / 3) * 64;
    int tid = threadIdx.x;
    int tx = tid & 31, ty = tid >> 5;
    float acc[8][8];
#pragma unroll
    for (int i = 0; i < 8; i++)
#pragma unroll
        for (int j = 0; j < 8; j++) acc[i][j] = 0.f;
    for (int cc = 0; cc < 4; cc++) {
        __syncthreads();
        for (int e = tid; e < 64 * 32; e += 256) {
            int ci = e & 31, i = e >> 5;
            Fs[i][ci] = F[(long)(tb0 + i) * 128 + cc * 32 + ci];
        }
        for (int e = tid; e < 32 * 256; e += 256) {
            int jj = e & 255, ci = e >> 8;
            Ws[ci][jj] = WxT[(cc * 32 + ci) * 768 + jt * 256 + jj];
        }
        __syncthreads();
        for (int ci = 0; ci < 32; ci++) {
            float a[8], w[8];
#pragma unroll
            for (int i = 0; i < 8; i++) a[i] = Fs[ty * 8 + i][ci];
            *(float4*)&w[0] = *(const float4*)&Ws[ci][tx * 8];
            *(float4*)&w[4] = *(const float4*)&Ws[ci][tx * 8 + 4];
#pragma unroll
            for (int i = 0; i < 8; i++)
#pragma unroll
                for (int j = 0; j < 8; j++) acc[i][j] = fmaf(a[i], w[j], acc[i][j]);
        }
    }
    float bj[8];
#pragma unroll
    for (int j = 0; j < 8; j++) {
        int col = jt * 256 + tx * 8 + j;
        bj[j] = bih[col] + (col < 512 ? bhh[col] : 0.f);
    }
#pragma unroll
    for (int i = 0; i < 8; i++) {
        float o[8];
#pragma unroll
        for (int j = 0; j < 8; j++) o[j] = acc[i][j] + bj[j];
        float* dst = &Gx[(long)(tb0 + ty * 8 + i) * 768 + jt * 256 + tx * 8];
        *(float4*)&dst[0] = *(float4*)&o[0];
        *(float4*)&dst[4] = *(float4*)&o[4];
    }
}

// ====== GRU v14: 3-tier residency + raw barriers + cross-barrier prefetch ======
// R13 accounting: 4680 cyc/step ~ stream(2690) + phases(~1500) SERIALIZED.
// Cause: __syncthreads emits s_waitcnt vmcnt(0) -- every barrier drains the
// weight stream and the early-issued Gx loads (the same drain mechanism as
// the m97 GEMM's ~20% stall). Fix: raw "lgkmcnt(0); s_barrier" (all cross-
// wave deps are LDS; precedent: R0's ring kernel) + prefetch the 8 rt5
// fragments for step t+1 before B1 (32 regs, in flight across gates/proj).
__global__ __attribute__((amdgpu_waves_per_eu(2, 2))) __launch_bounds__(512) void k_gru2(
    const f16x8* __restrict__ Wp8, const float* __restrict__ Gx,
    const float* __restrict__ Wih, const float* __restrict__ bhh_g,
    const float* __restrict__ Wf, const float* __restrict__ bf_g,
    const float* __restrict__ targets, const unsigned char* __restrict__ fmask,
    const int* __restrict__ flag, float* __restrict__ out)
{
    extern __shared__ __align__(16) _Float16 dynw[];   // [15][512] f16x8
    __shared__ __align__(16) float hq[320];      // swizzled fp32 h (proj)
    __shared__ __align__(16) _Float16 hqh[256];  // fp16(h)      (B col 0)
    __shared__ __align__(16) _Float16 hqh2[256]; // h - fp16(h)  (B col 1)
    __shared__ __align__(16) float gsum[768];
    __shared__ float tfl[16];
    __shared__ __align__(16) _Float16 wtfL[7680]; // [cp(30)][256] fp16
    __shared__ __align__(16) float WfL[3200];    // [oc(10)][seg*20], padded
    const int b = blockIdx.x, tid = threadIdx.x;
    const int wv = tid >> 6, l = tid & 63;       // wave 0..7
    const int kg = l >> 4;                       // k-group within wave
    const int cl = l & 15;                       // MFMA column of this lane
    const bool isGate = (tid < 256);
    const bool isProj = (tid >= 256 && tid < 416);
    const int oc = (tid - 256) >> 4, seg = tid & 15;
    const bool isWr = isProj && (seg == 15);
    f16x8* wlds = (f16x8*)dynw;

    const f16x8* wp = Wp8 + (long)(wv * 48) * 64 + l;

    // ---- tier 1: 12 pinned reg fragments (q 0..11) ----
    f16x8 wq[12];
#pragma unroll
    for (int q = 0; q < 12; q++) wq[q] = wp[q * 64];
#pragma unroll
    for (int q = 0; q < 12; q++) asm volatile("" : "+v"(wq[q]));

    // ---- tier 2: 15 LDS fragments (q 12..26), one-time fill ----
#pragma unroll
    for (int fi = 0; fi < 15; fi++) wlds[fi * 512 + tid] = wp[(12 + fi) * 64];

    // ---- one-time LDS fills ----
    for (int e = tid; e < 7680; e += 512) {
        int cp = e >> 8, jj = e & 255;
        int gg = cp / 10, c = cp - gg * 10;
        wtfL[e] = (_Float16)Wih[(gg * 256 + jj) * 138 + 128 + c];
    }
    for (int e = tid; e < 3200; e += 512) {
        int oo = e / 320, rem = e - oo * 320;
        int sg = rem / 20, ii = rem - sg * 20;
        WfL[e] = (ii < 16) ? Wf[oo * 256 + sg * 16 + ii] : 0.f;
    }
    for (int e = tid; e < 768; e += 512) gsum[e] = 0.f;
    if (tid < 320) hq[tid] = 0.f;
    if (tid < 256) { hqh[tid] = (_Float16)0.f; hqh2[tid] = (_Float16)0.f; }
    if (tid < 16) tfl[tid] = 0.f;
    float bfc = isProj ? bf_g[oc] : 0.f;
    float bh2 = isGate ? bhh_g[tid + 512] : 0.f;  // bhh_n (not foldable)
    const int int32mode = flag[0];
    float hold = 0.f;                            // gate thread's h[tid]
    const _Float16* bsrc = (cl == 1) ? hqh2 : hqh;

    // ---- prologue prefetch: rt5 fragments (q 40..47) for step 0 ----
    f16x8 pf[8];
#pragma unroll
    for (int q = 0; q < 8; q++) pf[q] = wp[(40 + q) * 64];
    __syncthreads();   // one-time full barrier after init

    for (int t = 0; t < 1024; t++) {
        float gxr = 0.f, gxz = 0.f, gxn = 0.f;
        if (isGate) {
            const float* gx = &Gx[((long)t * 32 + b) * 768];
            gxr = gx[tid]; gxz = gx[tid + 256]; gxn = gx[tid + 512];
        }
        float tgt = 0.f; int fmv = 0;
        if (isWr) {
            tgt = targets[((long)b * 1024 + t) * 10 + oc];
            fmv = int32mode ? ((const int*)fmask)[t * 32 + b] : (int)fmask[t * 32 + b];
        }

        f4 acc[6];
#pragma unroll
        for (int rt = 0; rt < 6; rt++) acc[rt] = (f4){0.f, 0.f, 0.f, 0.f};
#pragma unroll
        for (int kt = 0; kt < 8; kt++) {
            f16x8 s4 = wp[(32 + kt) * 64];
            f16x8 s3;
            if (kt >= 3) s3 = wp[(24 + kt) * 64];
            f16x8 bv = *(const f16x8*)&bsrc[kt * 32 + kg * 8];
            acc[0] = __builtin_amdgcn_mfma_f32_16x16x32_f16(wq[kt], bv, acc[0], 0, 0, 0);
            if (kt < 4)
                acc[1] = __builtin_amdgcn_mfma_f32_16x16x32_f16(wq[8 + kt], bv, acc[1], 0, 0, 0);
            else
                acc[1] = __builtin_amdgcn_mfma_f32_16x16x32_f16(wlds[(kt - 4) * 512 + tid], bv, acc[1], 0, 0, 0);
            acc[2] = __builtin_amdgcn_mfma_f32_16x16x32_f16(wlds[(4 + kt) * 512 + tid], bv, acc[2], 0, 0, 0);
            if (kt < 3)
                acc[3] = __builtin_amdgcn_mfma_f32_16x16x32_f16(wlds[(12 + kt) * 512 + tid], bv, acc[3], 0, 0, 0);
            else
                acc[3] = __builtin_amdgcn_mfma_f32_16x16x32_f16(s3, bv, acc[3], 0, 0, 0);
            acc[4] = __builtin_amdgcn_mfma_f32_16x16x32_f16(s4, bv, acc[4], 0, 0, 0);
            acc[5] = __builtin_amdgcn_mfma_f32_16x16x32_f16(pf[kt], bv, acc[5], 0, 0, 0);
        }
#pragma unroll
        for (int rt = 0; rt < 6; rt++) {
#pragma unroll
            for (int c = 0; c < 4; c++) acc[rt][c] = dpp_add<0x111>(acc[rt][c]);
        }
        if (cl == 1) {
#pragma unroll
            for (int rt = 0; rt < 6; rt++)
                *(f4*)&gsum[(wv * 6 + rt) * 16 + kg * 4] = acc[rt];
        }
        // prefetch rt5 fragments for step t+1; in flight across B1+gates+B2
#pragma unroll
        for (int q = 0; q < 8; q++) pf[q] = wp[(40 + q) * 64];

        RAW_BAR();   // B1: gsum ready; hqh/hqh2 reads of step t complete

        if (isGate) {
            float gr = gxr, gz = gxz, gn = gxn;
#pragma unroll
            for (int c = 0; c < 10; c++) {
                float tv = tfl[c];
                gr = fmaf(tv, (float)wtfL[c * 256 + tid], gr);
                gz = fmaf(tv, (float)wtfL[(10 + c) * 256 + tid], gz);
                gn = fmaf(tv, (float)wtfL[(20 + c) * 256 + tid], gn);
            }
            float ar = gsum[tid];
            float az = gsum[tid + 256];
            float an = gsum[tid + 512] + bh2;
            float r = 1.0f / (1.0f + expf(-(gr + ar)));
            float z = 1.0f / (1.0f + expf(-(gz + az)));
            float n = tanhf(fmaf(r, an, gn));
            float hnew = (1.0f - z) * n + z * hold;
            hold = hnew;
            _Float16 hh = (_Float16)hnew;
            hq[HQ(tid)] = hnew;
            hqh[tid] = hh;
            hqh2[tid] = (_Float16)(hnew - (float)hh);
        }
        RAW_BAR();   // B2: h ready

        if (isProj) {
            float s = 0.f;
#pragma unroll
            for (int qq = 0; qq < 4; qq++) {
                f4 h4 = *(const f4*)&hq[seg * 20 + qq * 4];
                f4 wvv = *(const f4*)&WfL[oc * 320 + seg * 20 + qq * 4];
                s = fmaf(wvv.x, h4.x, s);
                s = fmaf(wvv.y, h4.y, s);
                s = fmaf(wvv.z, h4.z, s);
                s = fmaf(wvv.w, h4.w, s);
            }
            s = dpp_add<0x111>(s);
            s = dpp_add<0x112>(s);
            s = dpp_add<0x114>(s);
            s = dpp_add<0x118>(s);
            if (isWr) {
                float o = s + bfc;
                out[((long)b * 1024 + t) * 10 + oc] = o;
                float pred = (o > 0.f) ? 1.f : 0.f;
                tfl[oc] = fmv ? tgt : pred;
            }
        }
        // ordering: gates(t) read gsum between B1(t) and B2(t); matvec(t+1)
        // writes gsum only after B2(t). matvec reads hqh/hqh2 after B2
        // (gates wrote before B2, ordered by lgkmcnt(0) in RAW_BAR). proj
        // reads hq/tfl between B2(t) and B1(t+1); gates touch them after
        // B1(t+1). Global loads (weights/Gx) are read-only; out writes are
        // per-thread-exclusive -- vmcnt need not drain at barriers.
    }
}

extern "C" void kernel_launch(void* const* d_in, const int* in_sizes, int n_in,
                              void* d_out, int out_size, void* d_ws, size_t ws_size,
                              hipStream_t stream) {
    (void)in_sizes; (void)n_in; (void)out_size; (void)ws_size;
    const float* features = (const float*)d_in[0];
    const float* targets  = (const float*)d_in[1];
    const unsigned char* fmask = (const unsigned char*)d_in[2];
    const float* W1  = (const float*)d_in[3];
    const float* b1  = (const float*)d_in[4];
    const float* g1  = (const float*)d_in[5];
    const float* be1 = (const float*)d_in[6];
    const float* m1  = (const float*)d_in[7];
    const float* v1  = (const float*)d_in[8];
    const float* W2  = (const float*)d_in[9];
    const float* b2  = (const float*)d_in[10];
    const float* g2  = (const float*)d_in[11];
    const float* be2 = (const float*)d_in[12];
    const float* m2  = (const float*)d_in[13];
    const float* v2  = (const float*)d_in[14];
    const float* W3  = (const float*)d_in[15];
    const float* b3  = (const float*)d_in[16];
    const float* g3  = (const float*)d_in[17];
    const float* be3 = (const float*)d_in[18];
    const float* m3  = (const float*)d_in[19];
    const float* v3  = (const float*)d_in[20];
    const float* Wih = (const float*)d_in[21];
    const float* Whh = (const float*)d_in[22];
    const float* bih = (const float*)d_in[23];
    const float* bhh = (const float*)d_in[24];
    const float* Wf  = (const float*)d_in[25];
    const float* bf  = (const float*)d_in[26];

    char* w = (char*)d_ws;
    unsigned int* WhhP = (unsigned int*)(w + 0);        // 393216 B (slot 786432)
    float* WxT = (float*)(w + 786432);                  // 393216 B
    _Float16* W2F = (_Float16*)(w + 1179648);           // 819200 B
    _Float16* W3Fh = (_Float16*)(w + 2818048);          // 819200 B
    _Float16* W3Fl = (_Float16*)(w + 3637248);          // 819200 B -> ends 4456448
    int*   flag = (int*)(w + 4456448);                  // 512 B slot
    _Float16* X1h = (_Float16*)(w + 4456960);           // 64 MB fp16
    _Float16* X1l = (_Float16*)(w + 4456960 + 67108864);// 64 MB fp16 residual
    float* Gx  = (float*)(w + 4456960);                 // 96 MB (reuses X1 after conv2)
    _Float16* X2h = (_Float16*)(w + 4456960 + 134217728);           // 16 MB
    _Float16* X2l = (_Float16*)(w + 4456960 + 134217728 + 16777216);// 16 MB
    float* F   = (float*)(w + 4456960 + 134217728 + 33554432); // 16 MB
    float* out = (float*)d_out;

    const int GRU_DYN_LDS = 15 * 512 * 16;              // 122880 B
    (void)hipFuncSetAttribute((const void*)k_gru2,
        hipFuncAttributeMaxDynamicSharedMemorySize, GRU_DYN_LDS);

    k_prep<<<1600, 256, 0, stream>>>(Wih, Whh, W2, W3, fmask, WhhP, WxT, W2F, W3Fh, W3Fl, flag);
    k_conv1<<<8192, 256, 0, stream>>>(features, W1, b1, g1, be1, m1, v1, X1h, X1l);
    k_conv2<<<4096, 256, 0, stream>>>(X1h, X1l, W2F, b2, g2, be2, m2, v2, X2h, X2l);
    k_conv3<<<4096, 256, 0, stream>>>(X2h, X2l, W3Fh, W3Fl, b3, g3, be3, m3, v3, F);
    k_gemm<<<1536, 256, 0, stream>>>(F, WxT, bih, bhh, Gx);
    k_gru2<<<32, 512, GRU_DYN_LDS, stream>>>((const f16x8*)WhhP, Gx, Wih, bhh, Wf, bf,
                                             targets, fmask, flag, out);
}

// Round 15
// 3076.259 us; speedup vs baseline: 1.0180x; 1.0180x over previous
//
#include <hip/hip_runtime.h>
#include <math.h>

#define EPSF 1e-5f

typedef __attribute__((ext_vector_type(2))) float f2;
typedef __attribute__((ext_vector_type(4))) float f4;
typedef __attribute__((ext_vector_type(8))) _Float16 f16x8;

// DPP helper: v += value from lane (i - N) within the 16-lane DPP row (0 if OOB)
template<int CTRL>
__device__ __forceinline__ float dpp_add(float v) {
    int s = __builtin_amdgcn_update_dpp(0, __float_as_int(v), CTRL, 0xf, 0xf, true);
    return v + __int_as_float(s);
}

// hq swizzle: +4 floats of pad per 16 (stride 20)
#define HQ(d) ((d) + (((d) >> 4) << 2))

// ---------------- prep: weight transposes + bool-dtype detect ----------------
// WhhP: MFMA A-fragment layout (tile-major). W2F/W3Fh/W3Fl: MFMA B-fragment
// layout [tap(25)][cc(4)][cot(8)][lane(64)][e(8)] fp16 (W3 split hi/lo exactly).
__global__ __launch_bounds__(256) void k_prep(
    const float* __restrict__ Wih, const float* __restrict__ Whh,
    const float* __restrict__ W2, const float* __restrict__ W3,
    const unsigned char* __restrict__ fmask,
    unsigned int* __restrict__ WhhP, float* __restrict__ WxT,
    _Float16* __restrict__ W2F, _Float16* __restrict__ W3Fh,
    _Float16* __restrict__ W3Fl, int* __restrict__ flag)
{
    int idx = blockIdx.x * 256 + threadIdx.x;
    if (idx < 98304) {                  // Whh -> MFMA A-frag layout
        int T = idx >> 8;
        int lane = (idx >> 2) & 63;
        int j = idx & 3;
        int RT = T >> 3, kt = T & 7;
        int row = RT * 16 + (lane & 15);
        int col = kt * 32 + (lane >> 4) * 8 + j * 2;
        union { _Float16 h[2]; unsigned int u; } pk;
        pk.h[0] = (_Float16)Whh[row * 256 + col];
        pk.h[1] = (_Float16)Whh[row * 256 + col + 1];
        WhhP[idx] = pk.u;
    }
    if (idx < 105984) {                 // Wih[768][138] x-part -> WxT[128][768]
        int j = idx / 138, k = idx % 138;
        if (k < 128) WxT[k * 768 + j] = Wih[idx];
    }
    if (idx < 409600) {                 // W2/W3 -> B-fragments
        int f = idx & 7, lane = (idx >> 3) & 63, cot = (idx >> 9) & 7;
        int cc = (idx >> 12) & 3, T = idx >> 14;     // T 0..24
        int k = cc * 32 + (lane >> 4) * 8 + f;
        int co = cot * 16 + (lane & 15);
        int dt = T / 5, dm = T % 5;
        W2F[idx] = (_Float16)W2[co * 3200 + k * 25 + dt * 5 + dm];
        float w3v = W3[co * 3200 + k * 25 + dt * 5 + dm];
        _Float16 h3 = (_Float16)w3v;
        W3Fh[idx] = h3;
        W3Fl[idx] = (_Float16)(w3v - (float)h3);
    }
    if (idx == 0) {                     // bool stored as int32?
        int nz = 0;
        for (int i = 0; i < 4096; i++) if ((i & 3) != 0) nz |= fmask[i];
        *flag = nz ? 0 : 1;
    }
}

// ------- conv1: [32,1,1024,40] -> X1h (fp16 hi) + X1l (fp16 residual) -------
__global__ __launch_bounds__(256) void k_conv1(
    const float* __restrict__ X, const float* __restrict__ W1,
    const float* __restrict__ bb, const float* __restrict__ gg,
    const float* __restrict__ be, const float* __restrict__ mm_,
    const float* __restrict__ vv, _Float16* __restrict__ X1h,
    _Float16* __restrict__ X1l)
{
    __shared__ __align__(16) float xs[8][44];
    __shared__ __align__(16) float ws[25][128];
    __shared__ float sc[128], sh[128];
    int bid = blockIdx.x;
    int b = bid >> 8, t0 = (bid & 255) << 2;
    int tid = threadIdx.x;
    for (int e = tid; e < 8 * 44; e += 256) {
        int tt = e / 44, mm = e % 44;
        int gt = t0 + tt - 2, gm = mm - 2;
        float val = 0.f;
        if (gt >= 0 && gt < 1024 && gm >= 0 && gm < 40)
            val = X[(b * 1024 + gt) * 40 + gm];
        xs[tt][mm] = val;
    }
    for (int e = tid; e < 3200; e += 256) {
        int tap = e >> 7, co = e & 127;
        ws[tap][co] = W1[co * 25 + tap];
    }
    if (tid < 128) {
        float s = gg[tid] / sqrtf(vv[tid] + EPSF);
        sc[tid] = s;
        sh[tid] = (bb[tid] - mm_[tid]) * s + be[tid];
    }
    __syncthreads();
    int cog = tid >> 5;          // 8 groups x 16 co
    int m1i = (tid >> 2) & 7;    // pooled mel
    int tp  = tid & 3;           // t'
    int co0 = cog * 16;
    float val[5][16];
#pragma unroll
    for (int p = 0; p < 5; p++)
#pragma unroll
        for (int i = 0; i < 16; i++) val[p][i] = 0.f;
#pragma unroll
    for (int dt = 0; dt < 5; dt++) {
#pragma unroll
        for (int dm = 0; dm < 5; dm++) {
            float w[16];
#pragma unroll
            for (int i = 0; i < 16; i += 4)
                *(float4*)&w[i] = *(const float4*)&ws[dt * 5 + dm][co0 + i];
#pragma unroll
            for (int p = 0; p < 5; p++) {
                float x = xs[tp + dt][m1i * 5 + p + dm];
#pragma unroll
                for (int i = 0; i < 16; i++) val[p][i] = fmaf(x, w[i], val[p][i]);
            }
        }
    }
    f16x8 h0, h1, l0, l1;
#pragma unroll
    for (int i = 0; i < 16; i++) {
        float s = sc[co0 + i], h = sh[co0 + i];
        float mx = 0.f;
#pragma unroll
        for (int p = 0; p < 5; p++) {
            float y = fmaf(val[p][i], s, h);
            y = fmaxf(y, 0.f);
            mx = fmaxf(mx, y);
        }
        _Float16 hh = (_Float16)mx;
        _Float16 ll = (_Float16)(mx - (float)hh);
        if (i < 8) { h0[i] = hh; l0[i] = ll; }
        else       { h1[i - 8] = hh; l1[i - 8] = ll; }
    }
    long off = (((long)(b * 1024 + t0 + tp)) * 8 + m1i) * 128 + co0;
    *(f16x8*)&X1h[off] = h0;
    *(f16x8*)&X1h[off + 8] = h1;
    *(f16x8*)&X1l[off] = l0;
    *(f16x8*)&X1l[off + 8] = l1;
}

// ====== conv2 v7b: MFMA implicit GEMM; outputs exact fp16 hi/lo X2 ======
__global__ __launch_bounds__(256) void k_conv2(
    const _Float16* __restrict__ X1h, const _Float16* __restrict__ X1l,
    const _Float16* __restrict__ W2F,
    const float* __restrict__ bb, const float* __restrict__ gg,
    const float* __restrict__ be, const float* __restrict__ mm_,
    const float* __restrict__ vv, _Float16* __restrict__ X2h,
    _Float16* __restrict__ X2l)
{
    __shared__ __align__(16) _Float16 xsh[144 * 40]; // hi tile
    __shared__ __align__(16) _Float16 xsl[144 * 40]; // lo tile
    __shared__ float sc[128], sh[128];
    int bid = blockIdx.x;
    int b = bid >> 7, t0 = (bid & 127) << 3;
    int tid = threadIdx.x;
    int wv = tid >> 6, l = tid & 63;
    int rowc = l & 15, ks = (l >> 4) << 3;
    int tloc = rowc >> 3, mloc = rowc & 7;
    if (tid < 128) {
        float s = gg[tid] / sqrtf(vv[tid] + EPSF);
        sc[tid] = s;
        sh[tid] = (bb[tid] - mm_[tid]) * s + be[tid];
    }
    f4 acc[4][2];
#pragma unroll
    for (int Mt = 0; Mt < 4; Mt++) {
        acc[Mt][0] = (f4){0.f, 0.f, 0.f, 0.f};
        acc[Mt][1] = (f4){0.f, 0.f, 0.f, 0.f};
    }

    for (int cc = 0; cc < 4; cc++) {
        __syncthreads();
        for (int e = tid; e < 1152; e += 256) {
            int w2 = (e >= 576) ? 1 : 0;
            int ee = e - 576 * w2;
            int r = ee >> 2, q = ee & 3;
            int tt = r / 12, mm2 = r % 12;
            int gt = t0 + tt - 2, gm = mm2 - 2;
            f16x8 v;
#pragma unroll
            for (int z = 0; z < 8; z++) v[z] = (_Float16)0.f;
            if (gt >= 0 && gt < 1024 && gm >= 0 && gm < 8) {
                const _Float16* src = w2 ? X1l : X1h;
                v = *(const f16x8*)&src[(((long)(b * 1024 + gt)) * 8 + gm) * 128 + cc * 32 + q * 8];
            }
            _Float16* dst = w2 ? xsl : xsh;
            *(f16x8*)&dst[r * 40 + q * 8] = v;
        }
        __syncthreads();
        for (int dt = 0; dt < 5; dt++) {
#pragma unroll
            for (int dm = 0; dm < 5; dm++) {
                const _Float16* wb = &W2F[(((long)((dt * 5 + dm) * 4 + cc) * 8) * 64) * 8];
                f16x8 b0 = *(const f16x8*)&wb[((wv * 2 + 0) * 64 + l) * 8];
                f16x8 b1 = *(const f16x8*)&wb[((wv * 2 + 1) * 64 + l) * 8];
#pragma unroll
                for (int Mt = 0; Mt < 4; Mt++) {
                    int ai = ((Mt * 2 + tloc + dt) * 12 + (mloc + dm)) * 40 + ks;
                    f16x8 ah = *(const f16x8*)&xsh[ai];
                    f16x8 al = *(const f16x8*)&xsl[ai];
                    acc[Mt][0] = __builtin_amdgcn_mfma_f32_16x16x32_f16(ah, b0, acc[Mt][0], 0, 0, 0);
                    acc[Mt][0] = __builtin_amdgcn_mfma_f32_16x16x32_f16(al, b0, acc[Mt][0], 0, 0, 0);
                    acc[Mt][1] = __builtin_amdgcn_mfma_f32_16x16x32_f16(ah, b1, acc[Mt][1], 0, 0, 0);
                    acc[Mt][1] = __builtin_amdgcn_mfma_f32_16x16x32_f16(al, b1, acc[Mt][1], 0, 0, 0);
                }
            }
        }
    }
    int g = l >> 4;
    int tof = g >> 1, m2 = g & 1;
#pragma unroll
    for (int Mt = 0; Mt < 4; Mt++) {
        int t = t0 + Mt * 2 + tof;
#pragma unroll
        for (int c2 = 0; c2 < 2; c2++) {
            int co = (wv * 2 + c2) * 16 + rowc;
            float s = sc[co], h = sh[co];
            f4 av = acc[Mt][c2];
            float mx = 0.f;
#pragma unroll
            for (int j = 0; j < 4; j++) {
                float y = fmaf(av[j], s, h);
                y = fmaxf(y, 0.f);
                mx = fmaxf(mx, y);
            }
            long oi = (((long)(b * 1024 + t)) * 2 + m2) * 128 + co;
            _Float16 hh = (_Float16)mx;
            X2h[oi] = hh;
            X2l[oi] = (_Float16)(mx - (float)hh);
        }
    }
}

// ====== conv3 v3: MFMA implicit GEMM, 3-pass exact hi/lo both operands ======
__global__ __launch_bounds__(256) void k_conv3(
    const _Float16* __restrict__ X2h, const _Float16* __restrict__ X2l,
    const _Float16* __restrict__ W3Fh, const _Float16* __restrict__ W3Fl,
    const float* __restrict__ bb, const float* __restrict__ gg,
    const float* __restrict__ be, const float* __restrict__ mm_,
    const float* __restrict__ vv, float* __restrict__ F)
{
    __shared__ __align__(16) _Float16 xsh[24 * 40];
    __shared__ __align__(16) _Float16 xsl[24 * 40];
    __shared__ float sc[128], sh[128];
    int bid = blockIdx.x;
    int b = bid >> 7, t0 = (bid & 127) << 3;
    int tid = threadIdx.x;
    int wv = tid >> 6, l = tid & 63;
    int rowc = l & 15, ks = (l >> 4) << 3;
    if (tid < 128) {
        float s = gg[tid] / sqrtf(vv[tid] + EPSF);
        sc[tid] = s;
        sh[tid] = (bb[tid] - mm_[tid]) * s + be[tid];
    }
    f4 acc[2];
    acc[0] = (f4){0.f, 0.f, 0.f, 0.f};
    acc[1] = (f4){0.f, 0.f, 0.f, 0.f};

    for (int cc = 0; cc < 4; cc++) {
        __syncthreads();
        for (int e = tid; e < 192; e += 256) {
            int w2 = (e >= 96) ? 1 : 0;
            int r = e - 96 * w2;
            int row = r >> 2, q = r & 3;
            int tt = row >> 1, mm2 = row & 1;
            int gt = t0 + tt - 2;
            f16x8 v;
#pragma unroll
            for (int z = 0; z < 8; z++) v[z] = (_Float16)0.f;
            if (gt >= 0 && gt < 1024) {
                const _Float16* src = w2 ? X2l : X2h;
                v = *(const f16x8*)&src[(((long)(b * 1024 + gt)) * 2 + mm2) * 128 + cc * 32 + q * 8];
            }
            _Float16* dst = w2 ? xsl : xsh;
            *(f16x8*)&dst[row * 40 + q * 8] = v;
        }
        __syncthreads();
        for (int dt = 0; dt < 5; dt++) {
#pragma unroll
            for (int dmi = 0; dmi < 3; dmi++) {
                int dm = dmi + 1;
                const long wb = (((long)((dt * 5 + dm) * 4 + cc) * 8) * 64) * 8;
                f16x8 b0h = *(const f16x8*)&W3Fh[wb + ((wv * 2 + 0) * 64 + l) * 8];
                f16x8 b0l = *(const f16x8*)&W3Fl[wb + ((wv * 2 + 0) * 64 + l) * 8];
                f16x8 b1h = *(const f16x8*)&W3Fh[wb + ((wv * 2 + 1) * 64 + l) * 8];
                f16x8 b1l = *(const f16x8*)&W3Fl[wb + ((wv * 2 + 1) * 64 + l) * 8];
                int mprime = (rowc & 1) + dm - 2;
                bool valid = (mprime >= 0) && (mprime <= 1);
                int row = rowc + dt * 2 + dm - 2;
                int ai = valid ? (row * 40 + ks) : 0;
                f16x8 ah = *(const f16x8*)&xsh[ai];
                f16x8 al = *(const f16x8*)&xsl[ai];
                if (!valid) {
#pragma unroll
                    for (int z = 0; z < 8; z++) { ah[z] = (_Float16)0.f; al[z] = (_Float16)0.f; }
                }
                acc[0] = __builtin_amdgcn_mfma_f32_16x16x32_f16(ah, b0h, acc[0], 0, 0, 0);
                acc[0] = __builtin_amdgcn_mfma_f32_16x16x32_f16(ah, b0l, acc[0], 0, 0, 0);
                acc[0] = __builtin_amdgcn_mfma_f32_16x16x32_f16(al, b0h, acc[0], 0, 0, 0);
                acc[1] = __builtin_amdgcn_mfma_f32_16x16x32_f16(ah, b1h, acc[1], 0, 0, 0);
                acc[1] = __builtin_amdgcn_mfma_f32_16x16x32_f16(ah, b1l, acc[1], 0, 0, 0);
                acc[1] = __builtin_amdgcn_mfma_f32_16x16x32_f16(al, b1h, acc[1], 0, 0, 0);
            }
        }
    }
    int g = l >> 4;
#pragma unroll
    for (int c2 = 0; c2 < 2; c2++) {
        int co = (wv * 2 + c2) * 16 + rowc;
        float s = sc[co], h = sh[co];
#pragma unroll
        for (int j2 = 0; j2 < 2; j2++) {
            float y0 = fmaxf(fmaf(acc[c2][j2 * 2], s, h), 0.f);
            float y1 = fmaxf(fmaf(acc[c2][j2 * 2 + 1], s, h), 0.f);
            F[((long)(t0 + g * 2 + j2) * 32 + b) * 128 + co] = fmaxf(y0, y1);
        }
    }
}

// ------- Gx = F @ Wihx.T + bih (+ bhh for r,z cols) : [32768,128]x[128,768] -------
__global__ __launch_bounds__(256) void k_gemm(
    const float* __restrict__ F, const float* __restrict__ WxT,
    const float* __restrict__ bih, const float* __restrict__ bhh,
    float* __restrict__ Gx)
{
    __shared__ __align__(16) float Fs[64][33];
    __shared__ __align__(16) float Ws[32][256];
    int bid = blockIdx.x;
    int jt = bid % 3, tb0 = (bid / 3) * 64;
    int tid = threadIdx.x;
    int tx = tid & 31, ty = tid >> 5;
    float acc[8][8];
#pragma unroll
    for (int i = 0; i < 8; i++)
#pragma unroll
        for (int j = 0; j < 8; j++) acc[i][j] = 0.f;
    for (int cc = 0; cc < 4; cc++) {
        __syncthreads();
        for (int e = tid; e < 64 * 32; e += 256) {
            int ci = e & 31, i = e >> 5;
            Fs[i][ci] = F[(long)(tb0 + i) * 128 + cc * 32 + ci];
        }
        for (int e = tid; e < 32 * 256; e += 256) {
            int jj = e & 255, ci = e >> 8;
            Ws[ci][jj] = WxT[(cc * 32 + ci) * 768 + jt * 256 + jj];
        }
        __syncthreads();
        for (int ci = 0; ci < 32; ci++) {
            float a[8], w[8];
#pragma unroll
            for (int i = 0; i < 8; i++) a[i] = Fs[ty * 8 + i][ci];
            *(float4*)&w[0] = *(const float4*)&Ws[ci][tx * 8];
            *(float4*)&w[4] = *(const float4*)&Ws[ci][tx * 8 + 4];
#pragma unroll
            for (int i = 0; i < 8; i++)
#pragma unroll
                for (int j = 0; j < 8; j++) acc[i][j] = fmaf(a[i], w[j], acc[i][j]);
        }
    }
    float bj[8];
#pragma unroll
    for (int j = 0; j < 8; j++) {
        int col = jt * 256 + tx * 8 + j;
        bj[j] = bih[col] + (col < 512 ? bhh[col] : 0.f);
    }
#pragma unroll
    for (int i = 0; i < 8; i++) {
        float o[8];
#pragma unroll
        for (int j = 0; j < 8; j++) o[j] = acc[i][j] + bj[j];
        float* dst = &Gx[(long)(tb0 + ty * 8 + i) * 768 + jt * 256 + tx * 8];
        *(float4*)&dst[0] = *(float4*)&o[0];
        *(float4*)&dst[4] = *(float4*)&o[4];
    }
}

// ====== GRU v13 (R13-exact, best measured: 1950us / total 3091us) ======
// R14 post-mortem: raw barriers + cross-barrier prefetch were NEUTRAL
// (2003us) -- the stream is not drain-bound; the per-step cost is a
// BALANCED pipeline (LDS-read issue ~550cyc, MFMA ~450cyc, stream ~170KB
// in parallel, serial gates+barriers ~800cyc). 3-tier weight residency at
// the 128-reg / 160KB-LDS capacity limits is the structural floor of the
// one-CU-per-batch sequential GRU (residency beyond this is closed:
// 10 allocator refusals, 256 arch-VGPR cap, AGPR-constraint garbage).
__global__ __attribute__((amdgpu_waves_per_eu(2, 2))) __launch_bounds__(512) void k_gru2(
    const f16x8* __restrict__ Wp8, const float* __restrict__ Gx,
    const float* __restrict__ Wih, const float* __restrict__ bhh_g,
    const float* __restrict__ Wf, const float* __restrict__ bf_g,
    const float* __restrict__ targets, const unsigned char* __restrict__ fmask,
    const int* __restrict__ flag, float* __restrict__ out)
{
    extern __shared__ __align__(16) _Float16 dynw[];   // [15][512] f16x8
    __shared__ __align__(16) float hq[320];      // swizzled fp32 h (proj)
    __shared__ __align__(16) _Float16 hqh[256];  // fp16(h)      (B col 0)
    __shared__ __align__(16) _Float16 hqh2[256]; // h - fp16(h)  (B col 1)
    __shared__ __align__(16) float gsum[768];
    __shared__ float tfl[16];
    __shared__ __align__(16) _Float16 wtfL[7680]; // [cp(30)][256] fp16
    __shared__ __align__(16) float WfL[3200];    // [oc(10)][seg*20], padded
    const int b = blockIdx.x, tid = threadIdx.x;
    const int wv = tid >> 6, l = tid & 63;       // wave 0..7
    const int kg = l >> 4;                       // k-group within wave
    const int cl = l & 15;                       // MFMA column of this lane
    const bool isGate = (tid < 256);
    const bool isProj = (tid >= 256 && tid < 416);
    const int oc = (tid - 256) >> 4, seg = tid & 15;
    const bool isWr = isProj && (seg == 15);
    f16x8* wlds = (f16x8*)dynw;

    const f16x8* wp = Wp8 + (long)(wv * 48) * 64 + l;

    // ---- tier 1: 12 pinned reg fragments (q 0..11) ----
    f16x8 wq[12];
#pragma unroll
    for (int q = 0; q < 12; q++) wq[q] = wp[q * 64];
#pragma unroll
    for (int q = 0; q < 12; q++) asm volatile("" : "+v"(wq[q]));

    // ---- tier 2: 15 LDS fragments (q 12..26), one-time fill ----
#pragma unroll
    for (int fi = 0; fi < 15; fi++) wlds[fi * 512 + tid] = wp[(12 + fi) * 64];

    // ---- one-time LDS fills ----
    for (int e = tid; e < 7680; e += 512) {
        int cp = e >> 8, jj = e & 255;
        int gg = cp / 10, c = cp - gg * 10;
        wtfL[e] = (_Float16)Wih[(gg * 256 + jj) * 138 + 128 + c];
    }
    for (int e = tid; e < 3200; e += 512) {
        int oo = e / 320, rem = e - oo * 320;
        int sg = rem / 20, ii = rem - sg * 20;
        WfL[e] = (ii < 16) ? Wf[oo * 256 + sg * 16 + ii] : 0.f;
    }
    for (int e = tid; e < 768; e += 512) gsum[e] = 0.f;
    if (tid < 320) hq[tid] = 0.f;
    if (tid < 256) { hqh[tid] = (_Float16)0.f; hqh2[tid] = (_Float16)0.f; }
    if (tid < 16) tfl[tid] = 0.f;
    float bfc = isProj ? bf_g[oc] : 0.f;
    float bh2 = isGate ? bhh_g[tid + 512] : 0.f;  // bhh_n (not foldable)
    const int int32mode = flag[0];
    float hold = 0.f;                            // gate thread's h[tid]
    const _Float16* bsrc = (cl == 1) ? hqh2 : hqh;
    __syncthreads();

    for (int t = 0; t < 1024; t++) {
        float gxr = 0.f, gxz = 0.f, gxn = 0.f;
        if (isGate) {
            const float* gx = &Gx[((long)t * 32 + b) * 768];
            gxr = gx[tid]; gxz = gx[tid + 256]; gxn = gx[tid + 512];
        }
        float tgt = 0.f; int fmv = 0;
        if (isWr) {
            tgt = targets[((long)b * 1024 + t) * 10 + oc];
            fmv = int32mode ? ((const int*)fmask)[t * 32 + b] : (int)fmask[t * 32 + b];
        }

        f4 acc[6];
#pragma unroll
        for (int rt = 0; rt < 6; rt++) acc[rt] = (f4){0.f, 0.f, 0.f, 0.f};
#pragma unroll
        for (int kt = 0; kt < 8; kt++) {
            f16x8 s4 = wp[(32 + kt) * 64];
            f16x8 s5 = wp[(40 + kt) * 64];
            f16x8 s3;
            if (kt >= 3) s3 = wp[(24 + kt) * 64];
            f16x8 bv = *(const f16x8*)&bsrc[kt * 32 + kg * 8];
            acc[0] = __builtin_amdgcn_mfma_f32_16x16x32_f16(wq[kt], bv, acc[0], 0, 0, 0);
            if (kt < 4)
                acc[1] = __builtin_amdgcn_mfma_f32_16x16x32_f16(wq[8 + kt], bv, acc[1], 0, 0, 0);
            else
                acc[1] = __builtin_amdgcn_mfma_f32_16x16x32_f16(wlds[(kt - 4) * 512 + tid], bv, acc[1], 0, 0, 0);
            acc[2] = __builtin_amdgcn_mfma_f32_16x16x32_f16(wlds[(4 + kt) * 512 + tid], bv, acc[2], 0, 0, 0);
            if (kt < 3)
                acc[3] = __builtin_amdgcn_mfma_f32_16x16x32_f16(wlds[(12 + kt) * 512 + tid], bv, acc[3], 0, 0, 0);
            else
                acc[3] = __builtin_amdgcn_mfma_f32_16x16x32_f16(s3, bv, acc[3], 0, 0, 0);
            acc[4] = __builtin_amdgcn_mfma_f32_16x16x32_f16(s4, bv, acc[4], 0, 0, 0);
            acc[5] = __builtin_amdgcn_mfma_f32_16x16x32_f16(s5, bv, acc[5], 0, 0, 0);
        }
#pragma unroll
        for (int rt = 0; rt < 6; rt++) {
#pragma unroll
            for (int c = 0; c < 4; c++) acc[rt][c] = dpp_add<0x111>(acc[rt][c]);
        }
        if (cl == 1) {
#pragma unroll
            for (int rt = 0; rt < 6; rt++)
                *(f4*)&gsum[(wv * 6 + rt) * 16 + kg * 4] = acc[rt];
        }
        __syncthreads();   // B1: gsum ready; hqh/hqh2 reads of step t complete

        if (isGate) {
            float gr = gxr, gz = gxz, gn = gxn;
#pragma unroll
            for (int c = 0; c < 10; c++) {
                float tv = tfl[c];
                gr = fmaf(tv, (float)wtfL[c * 256 + tid], gr);
                gz = fmaf(tv, (float)wtfL[(10 + c) * 256 + tid], gz);
                gn = fmaf(tv, (float)wtfL[(20 + c) * 256 + tid], gn);
            }
            float ar = gsum[tid];
            float az = gsum[tid + 256];
            float an = gsum[tid + 512] + bh2;
            float r = 1.0f / (1.0f + expf(-(gr + ar)));
            float z = 1.0f / (1.0f + expf(-(gz + az)));
            float n = tanhf(fmaf(r, an, gn));
            float hnew = (1.0f - z) * n + z * hold;
            hold = hnew;
            _Float16 hh = (_Float16)hnew;
            hq[HQ(tid)] = hnew;
            hqh[tid] = hh;
            hqh2[tid] = (_Float16)(hnew - (float)hh);
        }
        __syncthreads();   // B2: h ready

        if (isProj) {
            float s = 0.f;
#pragma unroll
            for (int qq = 0; qq < 4; qq++) {
                f4 h4 = *(const f4*)&hq[seg * 20 + qq * 4];
                f4 wvv = *(const f4*)&WfL[oc * 320 + seg * 20 + qq * 4];
                s = fmaf(wvv.x, h4.x, s);
                s = fmaf(wvv.y, h4.y, s);
                s = fmaf(wvv.z, h4.z, s);
                s = fmaf(wvv.w, h4.w, s);
            }
            s = dpp_add<0x111>(s);
            s = dpp_add<0x112>(s);
            s = dpp_add<0x114>(s);
            s = dpp_add<0x118>(s);
            if (isWr) {
                float o = s + bfc;
                out[((long)b * 1024 + t) * 10 + oc] = o;
                float pred = (o > 0.f) ? 1.f : 0.f;
                tfl[oc] = fmv ? tgt : pred;
            }
        }
    }
}

extern "C" void kernel_launch(void* const* d_in, const int* in_sizes, int n_in,
                              void* d_out, int out_size, void* d_ws, size_t ws_size,
                              hipStream_t stream) {
    (void)in_sizes; (void)n_in; (void)out_size; (void)ws_size;
    const float* features = (const float*)d_in[0];
    const float* targets  = (const float*)d_in[1];
    const unsigned char* fmask = (const unsigned char*)d_in[2];
    const float* W1  = (const float*)d_in[3];
    const float* b1  = (const float*)d_in[4];
    const float* g1  = (const float*)d_in[5];
    const float* be1 = (const float*)d_in[6];
    const float* m1  = (const float*)d_in[7];
    const float* v1  = (const float*)d_in[8];
    const float* W2  = (const float*)d_in[9];
    const float* b2  = (const float*)d_in[10];
    const float* g2  = (const float*)d_in[11];
    const float* be2 = (const float*)d_in[12];
    const float* m2  = (const float*)d_in[13];
    const float* v2  = (const float*)d_in[14];
    const float* W3  = (const float*)d_in[15];
    const float* b3  = (const float*)d_in[16];
    const float* g3  = (const float*)d_in[17];
    const float* be3 = (const float*)d_in[18];
    const float* m3  = (const float*)d_in[19];
    const float* v3  = (const float*)d_in[20];
    const float* Wih = (const float*)d_in[21];
    const float* Whh = (const float*)d_in[22];
    const float* bih = (const float*)d_in[23];
    const float* bhh = (const float*)d_in[24];
    const float* Wf  = (const float*)d_in[25];
    const float* bf  = (const float*)d_in[26];

    char* w = (char*)d_ws;
    unsigned int* WhhP = (unsigned int*)(w + 0);        // 393216 B (slot 786432)
    float* WxT = (float*)(w + 786432);                  // 393216 B
    _Float16* W2F = (_Float16*)(w + 1179648);           // 819200 B
    _Float16* W3Fh = (_Float16*)(w + 2818048);          // 819200 B
    _Float16* W3Fl = (_Float16*)(w + 3637248);          // 819200 B -> ends 4456448
    int*   flag = (int*)(w + 4456448);                  // 512 B slot
    _Float16* X1h = (_Float16*)(w + 4456960);           // 64 MB fp16
    _Float16* X1l = (_Float16*)(w + 4456960 + 67108864);// 64 MB fp16 residual
    float* Gx  = (float*)(w + 4456960);                 // 96 MB (reuses X1 after conv2)
    _Float16* X2h = (_Float16*)(w + 4456960 + 134217728);           // 16 MB
    _Float16* X2l = (_Float16*)(w + 4456960 + 134217728 + 16777216);// 16 MB
    float* F   = (float*)(w + 4456960 + 134217728 + 33554432); // 16 MB
    float* out = (float*)d_out;

    const int GRU_DYN_LDS = 15 * 512 * 16;              // 122880 B
    (void)hipFuncSetAttribute((const void*)k_gru2,
        hipFuncAttributeMaxDynamicSharedMemorySize, GRU_DYN_LDS);

    k_prep<<<1600, 256, 0, stream>>>(Wih, Whh, W2, W3, fmask, WhhP, WxT, W2F, W3Fh, W3Fl, flag);
    k_conv1<<<8192, 256, 0, stream>>>(features, W1, b1, g1, be1, m1, v1, X1h, X1l);
    k_conv2<<<4096, 256, 0, stream>>>(X1h, X1l, W2F, b2, g2, be2, m2, v2, X2h, X2l);
    k_conv3<<<4096, 256, 0, stream>>>(X2h, X2l, W3Fh, W3Fl, b3, g3, be3, m3, v3, F);
    k_gemm<<<1536, 256, 0, stream>>>(F, WxT, bih, bhh, Gx);
    k_gru2<<<32, 512, GRU_DYN_LDS, stream>>>((const f16x8*)WhhP, Gx, Wih, bhh, Wf, bf,
                                             targets, fmask, flag, out);
}